// Round 5
// baseline (920.804 us; speedup 1.0000x reference)
//
#include <hip/hip_runtime.h>

#define Bn 2
#define Nn 100000
#define DIM 128
#define En 600000
#define MTOT (Bn * Nn)   // 200000 nodes total
#define DPB 32           // dsts per fused-accum block (Nn/DPB = 3125 exact)

typedef __attribute__((ext_vector_type(8))) short bf16x8;
typedef __attribute__((ext_vector_type(4))) float f32x4;

__device__ __forceinline__ unsigned short f2bf(float f) {
    union { float f; unsigned u; } v; v.f = f;
    unsigned r = v.u + 0x7fffu + ((v.u >> 16) & 1u);   // RNE
    return (unsigned short)(r >> 16);
}
__device__ __forceinline__ float bf2f(unsigned u16) {
    union { unsigned u; float f; } v; v.u = u16 << 16; return v.f;
}
__device__ __forceinline__ float bf_lo(unsigned u) {
    union { unsigned u; float f; } v; v.u = u << 16; return v.f;
}
__device__ __forceinline__ float bf_hi(unsigned u) {
    union { unsigned u; float f; } v; v.u = u & 0xffff0000u; return v.f;
}

// ---------------- x -> bf16 ----------------
__global__ __launch_bounds__(256) void cvt_x_kernel(const float4* __restrict__ x,
                                                    ushort4* __restrict__ xbf) {
    int i = blockIdx.x * 256 + threadIdx.x;           // MTOT*128/4 = 6.4M exact
    float4 v = x[i];
    ushort4 o;
    o.x = f2bf(v.x); o.y = f2bf(v.y); o.z = f2bf(v.z); o.w = f2bf(v.w);
    xbf[i] = o;
}

// ---------------- [w;gw] -> bf16 (all 3 relations, one launch) -------------
__global__ __launch_bounds__(256) void cvt_w_kernel(
    const float* __restrict__ w0,  const float* __restrict__ gw0,
    const float* __restrict__ w1,  const float* __restrict__ gw1,
    const float* __restrict__ w2,  const float* __restrict__ gw2,
    unsigned short* __restrict__ WB)                  // [3][384][128]
{
    int idx = blockIdx.x * 256 + threadIdx.x;         // 3*49152
    int r = idx / 49152;
    int j = idx - r * 49152;
    const float* w  = (r == 0) ? w0  : (r == 1 ? w1  : w2);
    const float* gw = (r == 0) ? gw0 : (r == 1 ? gw1 : gw2);
    float v = (j < 128 * 128) ? w[j] : gw[j - 128 * 128];
    WB[idx] = f2bf(v);
}

// ---------------- CSR build: count ----------------
__global__ __launch_bounds__(256) void count_kernel(
    const int* __restrict__ e0, const int* __restrict__ e1, const int* __restrict__ e2,
    int* __restrict__ counts)                         // [3][Nn]
{
    int idx = blockIdx.x * 256 + threadIdx.x;
    if (idx >= 3 * En) return;
    int r = (idx >= 2 * En) ? 2 : (idx >= En ? 1 : 0);
    int e = idx - r * En;
    const int* ed = (r == 0) ? e0 : (r == 1 ? e1 : e2);
    int dst = ed[En + e];
    atomicAdd(&counts[r * Nn + dst], 1);
}

// ---------------- bucket allocator: wave-aggregated, no scan ---------------
#define WPR 1563   // waves per relation = ceil(Nn/64)
__global__ __launch_bounds__(256) void alloc_kernel(
    const int* __restrict__ counts,                   // [3][Nn]
    int* __restrict__ starts,                         // [3][Nn]
    int* __restrict__ gcursor)                        // [3]
{
    int wid  = blockIdx.x * 4 + (threadIdx.x >> 6);
    int lane = threadIdx.x & 63;
    int r = wid / WPR;
    if (r >= 3) return;                               // whole wave exits
    int dst = (wid - r * WPR) * 64 + lane;
    int c = (dst < Nn) ? counts[r * Nn + dst] : 0;

    int inc = c;                                      // inclusive prefix
#pragma unroll
    for (int d = 1; d < 64; d <<= 1) {
        int v = __shfl_up(inc, d);
        if (lane >= d) inc += v;
    }
    int total = __shfl(inc, 63);
    int base = 0;
    if (lane == 63) base = atomicAdd(&gcursor[r], total);
    base = __shfl(base, 63);

    if (dst < Nn) starts[r * Nn + dst] = base + inc - c;
}

// ---------------- CSR build: fill ----------------
__global__ __launch_bounds__(256) void fill_kernel(
    const int* __restrict__ e0, const int* __restrict__ e1, const int* __restrict__ e2,
    const int* __restrict__ starts,                   // [3][Nn]
    int* __restrict__ cursor,                         // [3][Nn]
    int* __restrict__ records)                        // [3][En] -> src
{
    int idx = blockIdx.x * 256 + threadIdx.x;
    if (idx >= 3 * En) return;
    int r = (idx >= 2 * En) ? 2 : (idx >= En ? 1 : 0);
    int e = idx - r * En;
    const int* ed = (r == 0) ? e0 : (r == 1 ? e1 : e2);
    int src = ed[e];
    int dst = ed[En + e];
    int pos = atomicAdd(&cursor[r * Nn + dst], 1);
    records[(size_t)r * En + starts[r * Nn + dst] + pos] = src;
}

// ---------------- node transform: A only (msg_lin = x W^T) -----------------
// 64 nodes/block, 4 waves, each wave owns 2 o-tiles (wave*32 .. wave*32+31).
// LDS-staged swizzled tile, then fully-coalesced uint4 writeout.
__global__ __launch_bounds__(256) void transformA_kernel(
    const short* __restrict__ Xbf,          // [MTOT][128]
    const short* __restrict__ WB,           // [128][128] = w (bf16)
    unsigned short* __restrict__ Abuf)
{
    __shared__ unsigned short tile[64 * 128];         // 16 KB
    const int tid  = threadIdx.x;
    const int wave = tid >> 6;
    const int lane = tid & 63;
    const int m = lane & 15;
    const int q = lane >> 4;
    const size_t nbase = (size_t)blockIdx.x * 64;

    bf16x8 a[4][4];
#pragma unroll
    for (int sub = 0; sub < 4; ++sub)
#pragma unroll
        for (int c = 0; c < 4; ++c)
            a[sub][c] = *(const bf16x8*)(Xbf + (nbase + (size_t)(sub * 16 + m)) * DIM + c * 32 + q * 8);

#pragma unroll
    for (int t = 0; t < 2; ++t) {
        const int ob = wave * 32 + t * 16;            // 0..112
        bf16x8 bfr[4];
#pragma unroll
        for (int c = 0; c < 4; ++c)
            bfr[c] = *(const bf16x8*)(WB + (size_t)(ob + m) * DIM + c * 32 + q * 8);

        const int o0 = ob + q * 4;
#pragma unroll
        for (int sub = 0; sub < 4; ++sub) {
            f32x4 acc = (f32x4){0.f, 0.f, 0.f, 0.f};
#pragma unroll
            for (int c = 0; c < 4; ++c)
                acc = __builtin_amdgcn_mfma_f32_16x16x32_bf16(bfr[c], a[sub][c], acc, 0, 0, 0);
            const int row = sub * 16 + m;
            ushort4 o4;
            o4.x = f2bf(acc[0]); o4.y = f2bf(acc[1]);
            o4.z = f2bf(acc[2]); o4.w = f2bf(acc[3]);
            *(ushort4*)&tile[row * 128 + (o0 ^ ((row & 7) << 3))] = o4;
        }
    }

    __syncthreads();

    const int r16 = tid >> 4;                         // 0..15
    const int c8  = (tid & 15) * 8;                   // ushort col 0..120
#pragma unroll
    for (int it = 0; it < 4; ++it) {
        const int row = it * 16 + r16;
        const int swz = (row & 7) << 3;
        const size_t node = nbase + (size_t)row;
        uint4 va = *(const uint4*)&tile[row * 128 + (c8 ^ swz)];
        *(uint4*)(Abuf + node * DIM + c8) = va;
    }
}

// ---------------- fused accum: compute S/M in-block, then gather -----------
// Block = 32 consecutive dsts. Phase 1: 64x128x256 MFMA GEMM (2 batches x 32
// contiguous dst rows of Xbf vs gw) -> S (o<128, sigmoid+gb) and M (o>=128,
// +gb) staged in swizzled LDS (32 KB). S/M never touch HBM. Phase 2: per-dst
// edge gather with readlane-broadcast src, 2-wide unrolled MLP.
template <int FIRST>
__global__ __launch_bounds__(256) void film_accum_kernel(
    const short* __restrict__ Xbf,          // [MTOT][128]
    const short* __restrict__ GWB,          // [256][128] = gw (bf16)
    const float* __restrict__ gb,           // [256]
    const unsigned short* __restrict__ Abuf,
    const int* __restrict__ starts,         // [Nn] (this relation)
    const int* __restrict__ counts,         // [Nn] (this relation)
    const int* __restrict__ records,        // [En] (this relation)
    float* __restrict__ out)                // [MTOT][128]
{
    __shared__ unsigned short smtile[64 * 256];       // 32 KB: [xrow][256]
    const int tid  = threadIdx.x;
    const int wave = tid >> 6;
    const int lane = tid & 63;
    const int m = lane & 15;
    const int q = lane >> 4;
    const int dbase = blockIdx.x * DPB;

    // ---- phase 1: S/M GEMM into LDS ----
    {
        bf16x8 a[4][4];                               // 4 row-tiles x 4 K-frags
#pragma unroll
        for (int rt = 0; rt < 4; ++rt) {
            const int i = rt * 16 + m;                // xrow 0..63
            const int b = i >> 5;
            const int local = i & 31;
            const size_t grow = (size_t)b * Nn + (size_t)(dbase + local);
#pragma unroll
            for (int c = 0; c < 4; ++c)
                a[rt][c] = *(const bf16x8*)(Xbf + grow * DIM + c * 32 + q * 8);
        }

        const int obase = wave * 64;                  // 0,64 = S ; 128,192 = M
#pragma unroll
        for (int t = 0; t < 4; ++t) {
            const int ot = obase + t * 16;
            bf16x8 bfr[4];
#pragma unroll
            for (int c = 0; c < 4; ++c)
                bfr[c] = *(const bf16x8*)(GWB + (size_t)(ot + m) * DIM + c * 32 + q * 8);

            const int o0 = ot + q * 4;                // 4 consecutive outs
            const float4 g = *(const float4*)(gb + o0);
#pragma unroll
            for (int rt = 0; rt < 4; ++rt) {
                f32x4 acc = (f32x4){0.f, 0.f, 0.f, 0.f};
#pragma unroll
                for (int c = 0; c < 4; ++c)
                    acc = __builtin_amdgcn_mfma_f32_16x16x32_bf16(bfr[c], a[rt][c], acc, 0, 0, 0);
                float v0 = acc[0] + g.x, v1 = acc[1] + g.y;
                float v2 = acc[2] + g.z, v3 = acc[3] + g.w;
                if (obase < 128) {                    // wave-uniform branch
                    v0 = 1.f / (1.f + __expf(-v0));
                    v1 = 1.f / (1.f + __expf(-v1));
                    v2 = 1.f / (1.f + __expf(-v2));
                    v3 = 1.f / (1.f + __expf(-v3));
                }
                const int xrow = rt * 16 + m;
                ushort4 o4;
                o4.x = f2bf(v0); o4.y = f2bf(v1); o4.z = f2bf(v2); o4.w = f2bf(v3);
                *(ushort4*)&smtile[xrow * 256 + (o0 ^ ((xrow & 7) << 3))] = o4;
            }
        }
    }

    __syncthreads();

    // ---- phase 2: gather-accumulate ----
    const int half = lane >> 5;             // batch index
    const int hl   = lane & 31;
    const int k    = hl * 4;                // 4 feats per lane
    const char* Abase = (const char*)(Abuf + (size_t)half * Nn * DIM + k);

    for (int ii = 0; ii < 8; ++ii) {
        const int dl  = wave * 8 + ii;                // 0..31
        const int dst = dbase + dl;
        const int cnt = counts[dst];
        if (!FIRST && cnt == 0) continue;
        const int beg = starts[dst];

        const int xrow = half * 32 + dl;
        const int swz  = (xrow & 7) << 3;
        const ushort4 sv = *(const ushort4*)&smtile[xrow * 256 + (k ^ swz)];
        const ushort4 mv = *(const ushort4*)&smtile[xrow * 256 + ((128 + k) ^ swz)];
        const float s0 = bf2f(sv.x), s1 = bf2f(sv.y), s2 = bf2f(sv.z), s3 = bf2f(sv.w);
        const float u0 = bf2f(mv.x), u1 = bf2f(mv.y), u2 = bf2f(mv.z), u3 = bf2f(mv.w);

        float a0 = 0.f, a1 = 0.f, a2 = 0.f, a3 = 0.f;
        float b0 = 0.f, b1 = 0.f, b2 = 0.f, b3 = 0.f;

        for (int base = 0; base < cnt; base += 64) {
            const int rem = cnt - base;
            const int nb  = rem < 64 ? rem : 64;
            int srcl = 0;
            if (lane < nb) srcl = records[beg + base + lane];

            int j = 0;
            for (; j + 1 < nb; j += 2) {
                const int sA = __builtin_amdgcn_readlane(srcl, j);
                const int sB = __builtin_amdgcn_readlane(srcl, j + 1);
                const uint2 avA = *(const uint2*)(Abase + (size_t)sA * (DIM * 2));
                const uint2 avB = *(const uint2*)(Abase + (size_t)sB * (DIM * 2));
                float r;
                r = fmaf(s0, bf_lo(avA.x), u0); a0 += fmaxf(r, 0.f);
                r = fmaf(s1, bf_hi(avA.x), u1); a1 += fmaxf(r, 0.f);
                r = fmaf(s2, bf_lo(avA.y), u2); a2 += fmaxf(r, 0.f);
                r = fmaf(s3, bf_hi(avA.y), u3); a3 += fmaxf(r, 0.f);
                r = fmaf(s0, bf_lo(avB.x), u0); b0 += fmaxf(r, 0.f);
                r = fmaf(s1, bf_hi(avB.x), u1); b1 += fmaxf(r, 0.f);
                r = fmaf(s2, bf_lo(avB.y), u2); b2 += fmaxf(r, 0.f);
                r = fmaf(s3, bf_hi(avB.y), u3); b3 += fmaxf(r, 0.f);
            }
            if (j < nb) {
                const int sA = __builtin_amdgcn_readlane(srcl, j);
                const uint2 avA = *(const uint2*)(Abase + (size_t)sA * (DIM * 2));
                float r;
                r = fmaf(s0, bf_lo(avA.x), u0); a0 += fmaxf(r, 0.f);
                r = fmaf(s1, bf_hi(avA.x), u1); a1 += fmaxf(r, 0.f);
                r = fmaf(s2, bf_lo(avA.y), u2); a2 += fmaxf(r, 0.f);
                r = fmaf(s3, bf_hi(avA.y), u3); a3 += fmaxf(r, 0.f);
            }
        }
        a0 += b0; a1 += b1; a2 += b2; a3 += b3;

        const size_t drow = ((size_t)half * Nn + (size_t)dst) * DIM;
        float4* op = (float4*)(out + drow + k);
        if (FIRST) {
            *op = make_float4(a0, a1, a2, a3);
        } else {
            float4 v = *op;
            v.x += a0; v.y += a1; v.z += a2; v.w += a3;
            *op = v;
        }
    }
}

// ---------------- fallback (ws too small): direct per-edge compute ---------
__global__ __launch_bounds__(128) void fallback_kernel(
    const float* __restrict__ x,
    const int* __restrict__ edges,
    const float* __restrict__ w,
    const float* __restrict__ gw,
    const float* __restrict__ gb,
    float* __restrict__ out)
{
    __shared__ float xs[DIM], xd[DIM];
    int be = blockIdx.x;
    int e = be >> 1, b = be & 1;
    int t = threadIdx.x;
    int src = edges[e], dst = edges[En + e];
    xs[t] = x[((size_t)b * Nn + src) * DIM + t];
    xd[t] = x[((size_t)b * Nn + dst) * DIM + t];
    __syncthreads();
    float ml = 0.f, om = gb[t], mu = gb[128 + t];
    for (int kk = 0; kk < DIM; ++kk) {
        float xsk = xs[kk], xdk = xd[kk];
        ml += w[t * DIM + kk] * xsk;
        om += gw[t * DIM + kk] * xdk;
        mu += gw[(128 + t) * DIM + kk] * xdk;
    }
    float s = 1.f / (1.f + __expf(-om));
    float msg = s * ml + mu;
    msg = msg > 0.f ? msg : 0.f;
    unsafeAtomicAdd(out + ((size_t)b * Nn + dst) * DIM + t, msg);
}

extern "C" void kernel_launch(void* const* d_in, const int* in_sizes, int n_in,
                              void* d_out, int out_size, void* d_ws, size_t ws_size,
                              hipStream_t stream) {
    const float* x    = (const float*)d_in[0];
    const int*   ed[3] = { (const int*)d_in[1],
                           (const int*)d_in[2],
                           (const int*)d_in[3] };
    const float* w[3]  = { (const float*)d_in[4], (const float*)d_in[7], (const float*)d_in[10] };
    const float* gw[3] = { (const float*)d_in[5], (const float*)d_in[8], (const float*)d_in[11] };
    const float* gb[3] = { (const float*)d_in[6], (const float*)d_in[9], (const float*)d_in[12] };
    float* out = (float*)d_out;

    const size_t xbf_sz  = (size_t)MTOT * DIM * 2;        // 51.2 MB
    const size_t wb_sz   = (size_t)3 * 384 * DIM * 2;     // 294 KB
    const size_t buf_sz  = (size_t)MTOT * DIM * 2;        // 51.2 MB (A only)
    const size_t cnt_sz  = (size_t)3 * Nn * 4;            // counts  1.2 MB
    const size_t cur_sz  = (size_t)3 * Nn * 4;            // cursor  1.2 MB
    const size_t gcu_sz  = 64;                            // 3 cursors, padded
    const size_t sta_sz  = (size_t)3 * Nn * 4;            // starts  1.2 MB
    const size_t rec_sz  = (size_t)3 * En * 4;            // records 7.2 MB
    const size_t need    = xbf_sz + wb_sz + buf_sz + cnt_sz + cur_sz + gcu_sz + sta_sz + rec_sz + 1024;

    if (ws_size >= need) {
        char* p = (char*)d_ws;
        short*          Xbf = (short*)p;              p += xbf_sz;
        unsigned short* WB  = (unsigned short*)p;     p += wb_sz;
        unsigned short* Ab  = (unsigned short*)p;     p += buf_sz;
        int*            counts  = (int*)p;            p += cnt_sz;
        int*            cursor  = (int*)p;            p += cur_sz;
        int*            gcursor = (int*)p;            p += gcu_sz;
        int*            starts  = (int*)p;            p += sta_sz;
        int*            records = (int*)p;

        // zero counts + cursor + gcursor (contiguous)
        hipMemsetAsync(counts, 0, cnt_sz + cur_sz + gcu_sz, stream);

        cvt_x_kernel<<<(MTOT * DIM / 4) / 256, 256, 0, stream>>>((const float4*)x, (ushort4*)Xbf);
        cvt_w_kernel<<<(3 * 384 * DIM) / 256, 256, 0, stream>>>(
            w[0], gw[0], w[1], gw[1], w[2], gw[2], WB);

        // CSR build (independent of transforms)
        count_kernel<<<(3 * En + 255) / 256, 256, 0, stream>>>(ed[0], ed[1], ed[2], counts);
        alloc_kernel<<<(3 * WPR + 3) / 4, 256, 0, stream>>>(counts, starts, gcursor);
        fill_kernel<<<(3 * En + 255) / 256, 256, 0, stream>>>(ed[0], ed[1], ed[2], starts, cursor, records);

        for (int r = 0; r < 3; ++r) {
            const unsigned short* WBr  = WB + (size_t)r * 384 * DIM;          // w rows
            const unsigned short* GWBr = WBr + (size_t)128 * DIM;             // gw rows
            transformA_kernel<<<MTOT / 64, 256, 0, stream>>>(
                Xbf, (const short*)WBr, Ab);
            const int* sta = starts + (size_t)r * Nn;
            const int* cnt = counts + (size_t)r * Nn;
            const int* rec = records + (size_t)r * En;
            if (r == 0)
                film_accum_kernel<1><<<Nn / DPB, 256, 0, stream>>>(
                    Xbf, (const short*)GWBr, gb[r], Ab, sta, cnt, rec, out);
            else
                film_accum_kernel<0><<<Nn / DPB, 256, 0, stream>>>(
                    Xbf, (const short*)GWBr, gb[r], Ab, sta, cnt, rec, out);
        }
    } else {
        hipMemsetAsync(d_out, 0, (size_t)MTOT * DIM * sizeof(float), stream);
        for (int r = 0; r < 3; ++r)
            fallback_kernel<<<En * Bn, 128, 0, stream>>>(x, ed[r], w[r], gw[r], gb[r], out);
    }
}

// Round 6
// 862.322 us; speedup vs baseline: 1.0678x; 1.0678x over previous
//
#include <hip/hip_runtime.h>

#define Bn 2
#define Nn 100000
#define DIM 128
#define En 600000
#define MTOT (Bn * Nn)   // 200000 nodes total
#define DPB 16           // dsts per fused-accum block (Nn/DPB = 6250 exact)

typedef __attribute__((ext_vector_type(8))) short bf16x8;
typedef __attribute__((ext_vector_type(4))) float f32x4;

__device__ __forceinline__ unsigned short f2bf(float f) {
    union { float f; unsigned u; } v; v.f = f;
    unsigned r = v.u + 0x7fffu + ((v.u >> 16) & 1u);   // RNE
    return (unsigned short)(r >> 16);
}
__device__ __forceinline__ float bf2f(unsigned u16) {
    union { unsigned u; float f; } v; v.u = u16 << 16; return v.f;
}
__device__ __forceinline__ float bf_lo(unsigned u) {
    union { unsigned u; float f; } v; v.u = u << 16; return v.f;
}
__device__ __forceinline__ float bf_hi(unsigned u) {
    union { unsigned u; float f; } v; v.u = u & 0xffff0000u; return v.f;
}

// ---------------- x -> bf16 ----------------
__global__ __launch_bounds__(256) void cvt_x_kernel(const float4* __restrict__ x,
                                                    ushort4* __restrict__ xbf) {
    int i = blockIdx.x * 256 + threadIdx.x;           // MTOT*128/4 = 6.4M exact
    float4 v = x[i];
    ushort4 o;
    o.x = f2bf(v.x); o.y = f2bf(v.y); o.z = f2bf(v.z); o.w = f2bf(v.w);
    xbf[i] = o;
}

// ---------------- [w;gw] -> bf16 (all 3 relations, one launch) -------------
__global__ __launch_bounds__(256) void cvt_w_kernel(
    const float* __restrict__ w0,  const float* __restrict__ gw0,
    const float* __restrict__ w1,  const float* __restrict__ gw1,
    const float* __restrict__ w2,  const float* __restrict__ gw2,
    unsigned short* __restrict__ WB)                  // [3][384][128]
{
    int idx = blockIdx.x * 256 + threadIdx.x;         // 3*49152
    int r = idx / 49152;
    int j = idx - r * 49152;
    const float* w  = (r == 0) ? w0  : (r == 1 ? w1  : w2);
    const float* gw = (r == 0) ? gw0 : (r == 1 ? gw1 : gw2);
    float v = (j < 128 * 128) ? w[j] : gw[j - 128 * 128];
    WB[idx] = f2bf(v);
}

// ---------------- CSR build: count ----------------
__global__ __launch_bounds__(256) void count_kernel(
    const int* __restrict__ e0, const int* __restrict__ e1, const int* __restrict__ e2,
    int* __restrict__ counts)                         // [3][Nn]
{
    int idx = blockIdx.x * 256 + threadIdx.x;
    if (idx >= 3 * En) return;
    int r = (idx >= 2 * En) ? 2 : (idx >= En ? 1 : 0);
    int e = idx - r * En;
    const int* ed = (r == 0) ? e0 : (r == 1 ? e1 : e2);
    int dst = ed[En + e];
    atomicAdd(&counts[r * Nn + dst], 1);
}

// ---------------- bucket allocator: wave-aggregated, no scan ---------------
#define WPR 1563   // waves per relation = ceil(Nn/64)
__global__ __launch_bounds__(256) void alloc_kernel(
    const int* __restrict__ counts,                   // [3][Nn]
    int* __restrict__ starts,                         // [3][Nn]
    int* __restrict__ gcursor)                        // [3]
{
    int wid  = blockIdx.x * 4 + (threadIdx.x >> 6);
    int lane = threadIdx.x & 63;
    int r = wid / WPR;
    if (r >= 3) return;                               // whole wave exits
    int dst = (wid - r * WPR) * 64 + lane;
    int c = (dst < Nn) ? counts[r * Nn + dst] : 0;

    int inc = c;                                      // inclusive prefix
#pragma unroll
    for (int d = 1; d < 64; d <<= 1) {
        int v = __shfl_up(inc, d);
        if (lane >= d) inc += v;
    }
    int total = __shfl(inc, 63);
    int base = 0;
    if (lane == 63) base = atomicAdd(&gcursor[r], total);
    base = __shfl(base, 63);

    if (dst < Nn) starts[r * Nn + dst] = base + inc - c;
}

// ---------------- CSR build: fill ----------------
__global__ __launch_bounds__(256) void fill_kernel(
    const int* __restrict__ e0, const int* __restrict__ e1, const int* __restrict__ e2,
    const int* __restrict__ starts,                   // [3][Nn]
    int* __restrict__ cursor,                         // [3][Nn]
    int* __restrict__ records)                        // [3][En] -> src
{
    int idx = blockIdx.x * 256 + threadIdx.x;
    if (idx >= 3 * En) return;
    int r = (idx >= 2 * En) ? 2 : (idx >= En ? 1 : 0);
    int e = idx - r * En;
    const int* ed = (r == 0) ? e0 : (r == 1 ? e1 : e2);
    int src = ed[e];
    int dst = ed[En + e];
    int pos = atomicAdd(&cursor[r * Nn + dst], 1);
    records[(size_t)r * En + starts[r * Nn + dst] + pos] = src;
}

// ---------------- node transform: A0,A1,A2 in ONE dispatch -----------------
// 64 nodes/block, 4 waves x 6 o-tiles = 24 tiles = 3 relations x 128 outs.
// widx in [0,384): r = widx>>7, o = widx&127, weight row = r*384 + o
// (WB layout is [3][384][128] with w in rows 0..127 of each relation block).
// LDS-staged 64x384 swizzled tile, then coalesced uint4 writeout to 3 bufs.
__global__ __launch_bounds__(256) void transformA_all_kernel(
    const short* __restrict__ Xbf,          // [MTOT][128]
    const short* __restrict__ WB,           // [3][384][128]
    unsigned short* __restrict__ Abuf)      // [3][MTOT][128]
{
    __shared__ unsigned short tile[64 * 384];         // 48 KB
    const int tid  = threadIdx.x;
    const int wave = tid >> 6;
    const int lane = tid & 63;
    const int m = lane & 15;
    const int q = lane >> 4;
    const size_t nbase = (size_t)blockIdx.x * 64;

    bf16x8 a[4][4];
#pragma unroll
    for (int sub = 0; sub < 4; ++sub)
#pragma unroll
        for (int c = 0; c < 4; ++c)
            a[sub][c] = *(const bf16x8*)(Xbf + (nbase + (size_t)(sub * 16 + m)) * DIM + c * 32 + q * 8);

#pragma unroll
    for (int t = 0; t < 6; ++t) {
        const int widx = wave * 96 + t * 16;          // 0..368
        const int r    = widx >> 7;
        const int o    = widx & 127;
        bf16x8 bfr[4];
#pragma unroll
        for (int c = 0; c < 4; ++c)
            bfr[c] = *(const bf16x8*)(WB + (size_t)(r * 384 + o + m) * DIM + c * 32 + q * 8);

        const int o0 = widx + q * 4;                  // tile col (0..383)
#pragma unroll
        for (int sub = 0; sub < 4; ++sub) {
            f32x4 acc = (f32x4){0.f, 0.f, 0.f, 0.f};
#pragma unroll
            for (int c = 0; c < 4; ++c)
                acc = __builtin_amdgcn_mfma_f32_16x16x32_bf16(bfr[c], a[sub][c], acc, 0, 0, 0);
            const int row = sub * 16 + m;
            ushort4 o4;
            o4.x = f2bf(acc[0]); o4.y = f2bf(acc[1]);
            o4.z = f2bf(acc[2]); o4.w = f2bf(acc[3]);
            *(ushort4*)&tile[row * 384 + (o0 ^ ((row & 7) << 3))] = o4;
        }
    }

    __syncthreads();

    const int r16 = tid >> 4;                         // 0..15
    const int c8  = (tid & 15) * 8;                   // ushort col 0..120
#pragma unroll
    for (int it = 0; it < 4; ++it) {
        const int row = it * 16 + r16;
        const int swz = (row & 7) << 3;
        const size_t node = nbase + (size_t)row;
#pragma unroll
        for (int r = 0; r < 3; ++r) {
            uint4 va = *(const uint4*)&tile[row * 384 + ((r * 128 + c8) ^ swz)];
            *(uint4*)(Abuf + (size_t)r * MTOT * DIM + node * DIM + c8) = va;
        }
    }
}

// ---------------- fused accum: compute S/M in-block, then gather -----------
// Block = 16 consecutive dsts (16 KB LDS -> 8 blocks/CU, full occupancy).
// Phase 1: 32x128x256 MFMA GEMM (2 batches x 16 dst rows of Xbf vs gw) ->
// S (o<128, sigmoid+gb) and M (o>=128, +gb) in swizzled LDS; S/M never
// touch HBM. Phase 2: per-dst gather with readlane-broadcast src indices.
template <int FIRST>
__global__ __launch_bounds__(256) void film_accum_kernel(
    const short* __restrict__ Xbf,          // [MTOT][128]
    const short* __restrict__ GWB,          // [256][128] = gw (bf16)
    const float* __restrict__ gb,           // [256]
    const unsigned short* __restrict__ Abuf,// [MTOT][128] (this relation)
    const int* __restrict__ starts,         // [Nn] (this relation)
    const int* __restrict__ counts,         // [Nn] (this relation)
    const int* __restrict__ records,        // [En] (this relation)
    float* __restrict__ out)                // [MTOT][128]
{
    __shared__ unsigned short smtile[32 * 256];       // 16 KB: [xrow][256]
    const int tid  = threadIdx.x;
    const int wave = tid >> 6;
    const int lane = tid & 63;
    const int m = lane & 15;
    const int q = lane >> 4;
    const int dbase = blockIdx.x * DPB;

    // ---- phase 1: S/M GEMM into LDS ----
    {
        bf16x8 a[2][4];                               // 2 row-tiles x 4 K-frags
#pragma unroll
        for (int rt = 0; rt < 2; ++rt) {
            const int i = rt * 16 + m;                // xrow 0..31
            const int b = i >> 4;
            const int local = i & 15;
            const size_t grow = (size_t)b * Nn + (size_t)(dbase + local);
#pragma unroll
            for (int c = 0; c < 4; ++c)
                a[rt][c] = *(const bf16x8*)(Xbf + grow * DIM + c * 32 + q * 8);
        }

        const int obase = wave * 64;                  // 0,64 = S ; 128,192 = M
#pragma unroll
        for (int t = 0; t < 4; ++t) {
            const int ot = obase + t * 16;
            bf16x8 bfr[4];
#pragma unroll
            for (int c = 0; c < 4; ++c)
                bfr[c] = *(const bf16x8*)(GWB + (size_t)(ot + m) * DIM + c * 32 + q * 8);

            const int o0 = ot + q * 4;                // 4 consecutive outs
            const float4 g = *(const float4*)(gb + o0);
#pragma unroll
            for (int rt = 0; rt < 2; ++rt) {
                f32x4 acc = (f32x4){0.f, 0.f, 0.f, 0.f};
#pragma unroll
                for (int c = 0; c < 4; ++c)
                    acc = __builtin_amdgcn_mfma_f32_16x16x32_bf16(bfr[c], a[rt][c], acc, 0, 0, 0);
                float v0 = acc[0] + g.x, v1 = acc[1] + g.y;
                float v2 = acc[2] + g.z, v3 = acc[3] + g.w;
                if (obase < 128) {                    // wave-uniform branch
                    v0 = 1.f / (1.f + __expf(-v0));
                    v1 = 1.f / (1.f + __expf(-v1));
                    v2 = 1.f / (1.f + __expf(-v2));
                    v3 = 1.f / (1.f + __expf(-v3));
                }
                const int xrow = rt * 16 + m;
                ushort4 o4;
                o4.x = f2bf(v0); o4.y = f2bf(v1); o4.z = f2bf(v2); o4.w = f2bf(v3);
                *(ushort4*)&smtile[xrow * 256 + (o0 ^ ((xrow & 7) << 3))] = o4;
            }
        }
    }

    __syncthreads();

    // ---- phase 2: gather-accumulate ----
    const int half = lane >> 5;             // batch index
    const int hl   = lane & 31;
    const int k    = hl * 4;                // 4 feats per lane
    const char* Abase = (const char*)(Abuf + (size_t)half * Nn * DIM + k);

    for (int ii = 0; ii < 4; ++ii) {
        const int dl  = wave * 4 + ii;                // 0..15
        const int dst = dbase + dl;
        const int cnt = counts[dst];
        if (!FIRST && cnt == 0) continue;
        const int beg = starts[dst];

        const int xrow = half * 16 + dl;              // 0..31
        const int swz  = (xrow & 7) << 3;
        const ushort4 sv = *(const ushort4*)&smtile[xrow * 256 + (k ^ swz)];
        const ushort4 mv = *(const ushort4*)&smtile[xrow * 256 + ((128 + k) ^ swz)];
        const float s0 = bf2f(sv.x), s1 = bf2f(sv.y), s2 = bf2f(sv.z), s3 = bf2f(sv.w);
        const float u0 = bf2f(mv.x), u1 = bf2f(mv.y), u2 = bf2f(mv.z), u3 = bf2f(mv.w);

        float a0 = 0.f, a1 = 0.f, a2 = 0.f, a3 = 0.f;
        float b0 = 0.f, b1 = 0.f, b2 = 0.f, b3 = 0.f;

        for (int base = 0; base < cnt; base += 64) {
            const int rem = cnt - base;
            const int nb  = rem < 64 ? rem : 64;
            int srcl = 0;
            if (lane < nb) srcl = records[beg + base + lane];

            int j = 0;
            for (; j + 1 < nb; j += 2) {
                const int sA = __builtin_amdgcn_readlane(srcl, j);
                const int sB = __builtin_amdgcn_readlane(srcl, j + 1);
                const uint2 avA = *(const uint2*)(Abase + (size_t)sA * (DIM * 2));
                const uint2 avB = *(const uint2*)(Abase + (size_t)sB * (DIM * 2));
                float r;
                r = fmaf(s0, bf_lo(avA.x), u0); a0 += fmaxf(r, 0.f);
                r = fmaf(s1, bf_hi(avA.x), u1); a1 += fmaxf(r, 0.f);
                r = fmaf(s2, bf_lo(avA.y), u2); a2 += fmaxf(r, 0.f);
                r = fmaf(s3, bf_hi(avA.y), u3); a3 += fmaxf(r, 0.f);
                r = fmaf(s0, bf_lo(avB.x), u0); b0 += fmaxf(r, 0.f);
                r = fmaf(s1, bf_hi(avB.x), u1); b1 += fmaxf(r, 0.f);
                r = fmaf(s2, bf_lo(avB.y), u2); b2 += fmaxf(r, 0.f);
                r = fmaf(s3, bf_hi(avB.y), u3); b3 += fmaxf(r, 0.f);
            }
            if (j < nb) {
                const int sA = __builtin_amdgcn_readlane(srcl, j);
                const uint2 avA = *(const uint2*)(Abase + (size_t)sA * (DIM * 2));
                float r;
                r = fmaf(s0, bf_lo(avA.x), u0); a0 += fmaxf(r, 0.f);
                r = fmaf(s1, bf_hi(avA.x), u1); a1 += fmaxf(r, 0.f);
                r = fmaf(s2, bf_lo(avA.y), u2); a2 += fmaxf(r, 0.f);
                r = fmaf(s3, bf_hi(avA.y), u3); a3 += fmaxf(r, 0.f);
            }
        }
        a0 += b0; a1 += b1; a2 += b2; a3 += b3;

        const size_t drow = ((size_t)half * Nn + (size_t)dst) * DIM;
        float4* op = (float4*)(out + drow + k);
        if (FIRST) {
            *op = make_float4(a0, a1, a2, a3);
        } else {
            float4 v = *op;
            v.x += a0; v.y += a1; v.z += a2; v.w += a3;
            *op = v;
        }
    }
}

// ---------------- fallback (ws too small): direct per-edge compute ---------
__global__ __launch_bounds__(128) void fallback_kernel(
    const float* __restrict__ x,
    const int* __restrict__ edges,
    const float* __restrict__ w,
    const float* __restrict__ gw,
    const float* __restrict__ gb,
    float* __restrict__ out)
{
    __shared__ float xs[DIM], xd[DIM];
    int be = blockIdx.x;
    int e = be >> 1, b = be & 1;
    int t = threadIdx.x;
    int src = edges[e], dst = edges[En + e];
    xs[t] = x[((size_t)b * Nn + src) * DIM + t];
    xd[t] = x[((size_t)b * Nn + dst) * DIM + t];
    __syncthreads();
    float ml = 0.f, om = gb[t], mu = gb[128 + t];
    for (int kk = 0; kk < DIM; ++kk) {
        float xsk = xs[kk], xdk = xd[kk];
        ml += w[t * DIM + kk] * xsk;
        om += gw[t * DIM + kk] * xdk;
        mu += gw[(128 + t) * DIM + kk] * xdk;
    }
    float s = 1.f / (1.f + __expf(-om));
    float msg = s * ml + mu;
    msg = msg > 0.f ? msg : 0.f;
    unsafeAtomicAdd(out + ((size_t)b * Nn + dst) * DIM + t, msg);
}

extern "C" void kernel_launch(void* const* d_in, const int* in_sizes, int n_in,
                              void* d_out, int out_size, void* d_ws, size_t ws_size,
                              hipStream_t stream) {
    const float* x    = (const float*)d_in[0];
    const int*   ed[3] = { (const int*)d_in[1],
                           (const int*)d_in[2],
                           (const int*)d_in[3] };
    const float* w[3]  = { (const float*)d_in[4], (const float*)d_in[7], (const float*)d_in[10] };
    const float* gw[3] = { (const float*)d_in[5], (const float*)d_in[8], (const float*)d_in[11] };
    const float* gb[3] = { (const float*)d_in[6], (const float*)d_in[9], (const float*)d_in[12] };
    float* out = (float*)d_out;

    const size_t xbf_sz  = (size_t)MTOT * DIM * 2;        // 51.2 MB
    const size_t wb_sz   = (size_t)3 * 384 * DIM * 2;     // 294 KB
    const size_t buf_sz  = (size_t)MTOT * DIM * 2;        // 51.2 MB per A buffer
    const size_t cnt_sz  = (size_t)3 * Nn * 4;            // counts  1.2 MB
    const size_t cur_sz  = (size_t)3 * Nn * 4;            // cursor  1.2 MB
    const size_t gcu_sz  = 64;                            // 3 cursors, padded
    const size_t sta_sz  = (size_t)3 * Nn * 4;            // starts  1.2 MB
    const size_t rec_sz  = (size_t)3 * En * 4;            // records 7.2 MB
    const size_t need    = xbf_sz + wb_sz + 3 * buf_sz + cnt_sz + cur_sz + gcu_sz + sta_sz + rec_sz + 1024;

    if (ws_size >= need) {
        char* p = (char*)d_ws;
        short*          Xbf = (short*)p;              p += xbf_sz;
        unsigned short* WB  = (unsigned short*)p;     p += wb_sz;
        unsigned short* Ab  = (unsigned short*)p;     p += 3 * buf_sz;
        int*            counts  = (int*)p;            p += cnt_sz;
        int*            cursor  = (int*)p;            p += cur_sz;
        int*            gcursor = (int*)p;            p += gcu_sz;
        int*            starts  = (int*)p;            p += sta_sz;
        int*            records = (int*)p;

        // zero counts + cursor + gcursor (contiguous)
        hipMemsetAsync(counts, 0, cnt_sz + cur_sz + gcu_sz, stream);

        cvt_x_kernel<<<(MTOT * DIM / 4) / 256, 256, 0, stream>>>((const float4*)x, (ushort4*)Xbf);
        cvt_w_kernel<<<(3 * 384 * DIM) / 256, 256, 0, stream>>>(
            w[0], gw[0], w[1], gw[1], w[2], gw[2], WB);

        // CSR build (independent of transforms)
        count_kernel<<<(3 * En + 255) / 256, 256, 0, stream>>>(ed[0], ed[1], ed[2], counts);
        alloc_kernel<<<(3 * WPR + 3) / 4, 256, 0, stream>>>(counts, starts, gcursor);
        fill_kernel<<<(3 * En + 255) / 256, 256, 0, stream>>>(ed[0], ed[1], ed[2], starts, cursor, records);

        // all three A = x W_r^T in one dispatch
        transformA_all_kernel<<<MTOT / 64, 256, 0, stream>>>(
            Xbf, (const short*)WB, Ab);

        for (int r = 0; r < 3; ++r) {
            const unsigned short* GWBr = WB + (size_t)r * 384 * DIM + (size_t)128 * DIM;
            const unsigned short* Abr  = Ab + (size_t)r * MTOT * DIM;
            const int* sta = starts + (size_t)r * Nn;
            const int* cnt = counts + (size_t)r * Nn;
            const int* rec = records + (size_t)r * En;
            if (r == 0)
                film_accum_kernel<1><<<Nn / DPB, 256, 0, stream>>>(
                    Xbf, (const short*)GWBr, gb[r], Abr, sta, cnt, rec, out);
            else
                film_accum_kernel<0><<<Nn / DPB, 256, 0, stream>>>(
                    Xbf, (const short*)GWBr, gb[r], Abr, sta, cnt, rec, out);
        }
    } else {
        hipMemsetAsync(d_out, 0, (size_t)MTOT * DIM * sizeof(float), stream);
        for (int r = 0; r < 3; ++r)
            fallback_kernel<<<En * Bn, 128, 0, stream>>>(x, ed[r], w[r], gw[r], gb[r], out);
    }
}